// Round 14
// baseline (134.418 us; speedup 1.0000x reference)
//
#include <hip/hip_runtime.h>
#include <hip/hip_bf16.h>

#define N_NODES 50000
#define N_EDGES 800000
#define D_IN 96
#define D_OUT 128
#define CAP 64              // deg ~ Poisson(16); P(deg>=64) ~ e^-41 -> no drops
#define CAPP 72             // bkt row pitch (u16): 144 B = 9*16 B (b128-aligned)

// Deterministic partition (R9-proven): bins of 64 nodes, fixed 24-slot
// sub-chunks, zero device atomics, zero memset. Cells padded to 128 B
// stride so the ingest uint4 is always one 64B-line pair, aligned.
#define NPB 64                                      // nodes per bin/agg block
#define N_BINS ((N_NODES + NPB - 1) / NPB)          // 782
#define CAP_SUB 24          // edges per (pblock,bin); lambda=4 -> P(ovf) ~3e-7
#define CAP_STRIDE 32       // u32 stride per cell = 128 B (line-aligned)
#define PART_EPB 3125
#define PART_BLOCKS (N_EDGES / PART_EPB)            // 256 exactly
#define PART_SLOTS 13                               // ceil(3125/256)

#define CONV_THREADS (N_NODES * 12)                 // 600000
#define CONV_BLOCKS ((CONV_THREADS + 255) / 256)    // 2344
#define WCONV_BLOCKS 12                             // 128*24 = 3072 = 12*256 tasks

#define AG_BLOCKS N_BINS                            // 782
#define AH_PITCH 104        // u16/row (96 + 8 pad); 208 B = 13*16 B (b128-aligned)
#define DH 48               // u16 per feature-half row (96 B)

typedef unsigned short u16;
typedef __attribute__((ext_vector_type(8))) short short8;   // 8 x bf16 (4 VGPRs)
typedef __attribute__((ext_vector_type(4))) float f32x4;

__device__ __forceinline__ u16 f2bf(float f) {
    unsigned u = __float_as_uint(f);
    unsigned r = (u + 0x7FFFu + ((u >> 16) & 1u)) >> 16;   // RNE
    return (u16)r;
}
__device__ __forceinline__ float bf2f(u16 h) {
    return __uint_as_float(((unsigned)h) << 16);
}

// ---------------------------------------------------------------------------
// K1: heterogeneous grid (structure R9-proven).
//   [0, PART_BLOCKS): deterministic partition, no device atomics.
//   [.., +CONV_BLOCKS): x -> FEATURE-SPLIT bf16: xh_lo = cols 0..47,
//     xh_hi = cols 48..95 (4.8 MB each). R13 lesson: 9.6 MB monolithic xh
//     vs 4 MB XCD-L2 -> 47% gather miss, agg pinned at ~45us across three
//     TLP variants; split halves the per-phase working set to L2-fittable.
//   [.., +WCONV_BLOCKS): Wfrag = bf16 B-fragment-layout [Wl|Wr].
// ---------------------------------------------------------------------------
__global__ __launch_bounds__(256) void sage_part_conv(
    const int* __restrict__ src,
    const int* __restrict__ dst,
    const float* __restrict__ x,
    const float* __restrict__ Wl,
    const float* __restrict__ Wr,
    u16* __restrict__ cnts,
    unsigned* __restrict__ binbuf,
    u16* __restrict__ xh_lo,
    u16* __restrict__ xh_hi,
    u16* __restrict__ Wfrag)
{
    __shared__ unsigned hist[N_BINS];
    __shared__ unsigned cur[N_BINS];

    const int b = blockIdx.x;
    const int tid = (int)threadIdx.x;

    if (b < PART_BLOCKS) {
        for (int i = tid; i < N_BINS; i += 256) { hist[i] = 0u; cur[i] = 0u; }
        __syncthreads();

        const int ebase = b * PART_EPB;
        const int e0 = ebase + tid;
        int d[PART_SLOTS], s[PART_SLOTS];
#pragma unroll
        for (int i = 0; i < PART_SLOTS; i++) {      // coalesced batch loads
            int valid = (tid + i * 256) < PART_EPB;
            int e = valid ? (e0 + i * 256) : ebase;
            d[i] = dst[e];
            s[i] = src[e];
        }
#pragma unroll
        for (int i = 0; i < PART_SLOTS; i++) {
            if ((tid + i * 256) < PART_EPB)
                atomicAdd(&hist[d[i] >> 6], 1u);    // LDS atomic (cheap)
        }
        __syncthreads();
        for (int i = tid; i < N_BINS; i += 256)     // plain-store counts
            cnts[(size_t)i * PART_BLOCKS + b] = (u16)hist[i];
#pragma unroll
        for (int i = 0; i < PART_SLOTS; i++) {
            if ((tid + i * 256) < PART_EPB) {
                int bn = d[i] >> 6;
                unsigned dl = (unsigned)(d[i] & 63);
                unsigned loc = atomicAdd(&cur[bn], 1u);      // LDS atomic
                if (loc < CAP_SUB)                  // ~3e-7 overflow guard
                    binbuf[((unsigned)bn * PART_BLOCKS + (unsigned)b) * CAP_STRIDE
                           + loc] = (dl << 16) | (unsigned)s[i];
            }
        }
    } else if (b < PART_BLOCKS + CONV_BLOCKS) {
        unsigned t = (unsigned)(b - PART_BLOCKS) * 256u + threadIdx.x;
        if (t >= (unsigned)CONV_THREADS) return;
        unsigned n = t / 12u;
        unsigned c8 = t - n * 12u;
        const float* p = x + (size_t)n * D_IN + c8 * 8u;
        short8 v;
#pragma unroll
        for (int i = 0; i < 8; i++) v[i] = (short)f2bf(p[i]);
        u16* dp = (c8 < 6) ? (xh_lo + (size_t)n * DH + c8 * 8u)
                           : (xh_hi + (size_t)n * DH + (c8 - 6) * 8u);
        *(short8*)dp = v;
    } else {
        // W -> bf16 fragments: 128 j x 24 chunks (12 Wl + 12 Wr)
        int idx = (b - PART_BLOCKS - CONV_BLOCKS) * 256 + tid;   // < 3072
        int j = idx / 24;
        int c8 = idx - j * 24;
        int kc = c8 >> 2;
        int quad = c8 & 3;
        const float* wsrc = (c8 < 12) ? (Wl + (size_t)j * D_IN + c8 * 8)
                                      : (Wr + (size_t)j * D_IN + (c8 - 12) * 8);
        int jt = j >> 4;
        int col = j & 15;
        short8 v;
#pragma unroll
        for (int i = 0; i < 8; i++) v[i] = (short)f2bf(wsrc[i]);
        *(short8*)(Wfrag + (((jt * 6 + kc) * 64) + col + 16 * quad) * 8) = v;
    }
}

// ---------------------------------------------------------------------------
// K2 (512-thread, split-K + shfl merge, FEATURE-PHASED gather):
// block j owns nodes [j*64,+64).
// R12/R13 post-mortem: three TLP variants all ~45us -> NOT concurrency
// bound; beyond-L2 gather bytes are the wall (~50 MB re-miss at the
// ~2 TB/s line-granular fabric rate). Fix: phase A tasks ordered so tasks
// 0..767 gather ONLY xh_lo (4.8 MB, L2-fittable) and 768..1535 ONLY xh_hi.
// Pair map: adjacent lanes = two edge-halves of one (m,chunk); merge via
// __shfl_xor(acc,1) (R13). 8-aligned split boundary (R11 alignment lesson).
// ---------------------------------------------------------------------------
__global__ __launch_bounds__(512) void sage_agg_gemm(
    const u16* __restrict__ xh_lo,
    const u16* __restrict__ xh_hi,
    const u16* __restrict__ cnts,
    const unsigned* __restrict__ binbuf,
    const u16* __restrict__ Wfrag,
    const float* __restrict__ bl,
    float* __restrict__ out)
{
    __shared__ __align__(16) u16 bkt[NPB * CAPP];   // 9216 B (padded rows)
    __shared__ unsigned cnt_l[NPB];                 // 256 B
    __shared__ __align__(16) u16 Ah[NPB * AH_PITCH];// 13312 B (total 22.8 KB)

    const int j = blockIdx.x;                       // bin == block
    const int tid = (int)threadIdx.x;
    const int n0 = j * NPB;

    if (tid < NPB) cnt_l[tid] = 0u;
    __syncthreads();

    // ---- prologue: threads 0-255 ingest sub-chunks (thread t = pblock t) --
    if (tid < PART_BLOCKS) {
        unsigned cnt_t = cnts[(size_t)j * PART_BLOCKS + tid];
        const uint4* sc = (const uint4*)(binbuf
                          + ((size_t)j * PART_BLOCKS + tid) * CAP_STRIDE);
        unsigned lim = cnt_t < CAP_SUB ? cnt_t : CAP_SUB;
        uint4 q0 = {0,0,0,0}, q1 = {0,0,0,0}, q2 = {0,0,0,0};
        uint4 q3 = {0,0,0,0}, q4 = {0,0,0,0}, q5 = {0,0,0,0};
        if (lim > 0)  q0 = sc[0];                   // exec-masked loads
        if (lim > 4)  q1 = sc[1];
        if (lim > 8)  q2 = sc[2];
        if (lim > 12) q3 = sc[3];
        if (lim > 16) q4 = sc[4];
        if (lim > 20) q5 = sc[5];
        unsigned buf[CAP_SUB];
        buf[0]=q0.x;  buf[1]=q0.y;  buf[2]=q0.z;  buf[3]=q0.w;
        buf[4]=q1.x;  buf[5]=q1.y;  buf[6]=q1.z;  buf[7]=q1.w;
        buf[8]=q2.x;  buf[9]=q2.y;  buf[10]=q2.z; buf[11]=q2.w;
        buf[12]=q3.x; buf[13]=q3.y; buf[14]=q3.z; buf[15]=q3.w;
        buf[16]=q4.x; buf[17]=q4.y; buf[18]=q4.z; buf[19]=q4.w;
        buf[20]=q5.x; buf[21]=q5.y; buf[22]=q5.z; buf[23]=q5.w;
#pragma unroll
        for (int e = 0; e < CAP_SUB; e++) {         // static indices (rule #20)
            if ((unsigned)e < lim) {
                unsigned w = buf[e];
                unsigned r = w >> 16;               // local node, < 64
                unsigned p = atomicAdd(&cnt_l[r], 1u);
                if (p < CAP) bkt[r * CAPP + p] = (u16)(w & 0xFFFFu);
            }
        }
    }
    __syncthreads();

    // ---- phase A: split-K aggregate, lo-half tasks first then hi-half ----
#pragma unroll
    for (int rep = 0; rep < 3; rep++) {
        int task = rep * 512 + tid;          // 0..1535
        int s = task >= 768 ? 1 : 0;         // 0: gather xh_lo; 1: xh_hi
        int t2 = task - s * 768;             // 0..767
        int m = t2 / 12;                     // node 0..63
        int rem = t2 - m * 12;
        int c8l = rem >> 1;                  // chunk-in-half 0..5
        int half = rem & 1;                  // edge-half (adjacent lanes)
        int c8 = s * 6 + c8l;                // global chunk 0..11 (Ah write)
        int n = n0 + m;
        const u16* xbase = s ? xh_hi : xh_lo;

        float acc[8];
#pragma unroll
        for (int i = 0; i < 8; i++) acc[i] = 0.0f;
        int deg = 0;

        if (n < N_NODES) {
            deg = (int)cnt_l[m];
            int dc = deg < CAP ? deg : CAP;
            // 8-ALIGNED split (ds_read_b128 needs 16B-aligned LDS addr)
            int mid = ((dc >> 1) + 4) & ~7;  // provably <= dc
            int e_lo = half ? mid : 0;
            int e_hi = half ? dc : mid;
            const u16* brow = bkt + m * CAPP;       // LDS (144B-pitch rows)
            int e = e_lo;                           // multiple of 8
            for (; e + 8 <= e_hi; e += 8) {
                short8 id = *(const short8*)(brow + e);   // aligned LDS b128
                short8 v[8];
#pragma unroll
                for (int q = 0; q < 8; q++) {
                    unsigned sidx = (u16)id[q];
                    v[q] = *(const short8*)(xbase + sidx * (unsigned)DH + c8l * 8u);
                }
#pragma unroll
                for (int q = 0; q < 8; q++)
#pragma unroll
                    for (int i = 0; i < 8; i++) acc[i] += bf2f((u16)v[q][i]);
            }
            if (e + 4 <= e_hi) {                    // scalar u16 index reads
                unsigned s0 = brow[e + 0];
                unsigned s1 = brow[e + 1];
                unsigned s2 = brow[e + 2];
                unsigned s3 = brow[e + 3];
                short8 v0 = *(const short8*)(xbase + s0 * (unsigned)DH + c8l * 8u);
                short8 v1 = *(const short8*)(xbase + s1 * (unsigned)DH + c8l * 8u);
                short8 v2 = *(const short8*)(xbase + s2 * (unsigned)DH + c8l * 8u);
                short8 v3 = *(const short8*)(xbase + s3 * (unsigned)DH + c8l * 8u);
#pragma unroll
                for (int i = 0; i < 8; i++)
                    acc[i] += bf2f((u16)v0[i]) + bf2f((u16)v1[i])
                            + bf2f((u16)v2[i]) + bf2f((u16)v3[i]);
                e += 4;
            }
            for (; e < e_hi; e++) {
                unsigned sidx = brow[e];
                short8 v = *(const short8*)(xbase + sidx * (unsigned)DH + c8l * 8u);
#pragma unroll
                for (int i = 0; i < 8; i++) acc[i] += bf2f((u16)v[i]);
            }
        }

        // merge halves across adjacent lanes (convergent: all lanes execute)
#pragma unroll
        for (int i = 0; i < 8; i++)
            acc[i] += __shfl_xor(acc[i], 1);

        if (half == 0) {                     // even lane finalizes + writes
            float invd = (n < N_NODES) ? 1.0f / fmaxf((float)deg, 1.0f) : 0.0f;
            short8 o;
#pragma unroll
            for (int i = 0; i < 8; i++)
                o[i] = (short)f2bf(acc[i] * invd);
            *(short8*)(Ah + m * AH_PITCH + c8 * 8) = o;
        }
    }
    __syncthreads();

    // ---- phase B: 8 waves; wave w = (tile w&3, jt-quad w>>2) ----
    const int wave = tid >> 6;
    const int lane = tid & 63;
    const int m16 = lane & 15;
    const int quad = lane >> 4;
    const int tile = wave & 3;
    const int jt0 = (wave >> 2) * 4;
    const int tilebase = n0 + tile * 16;
    if (tilebase >= N_NODES) return;         // all barriers already passed

    int nn = tilebase + m16;
    nn = nn < N_NODES ? nn : N_NODES - 1;    // clamp A-row source (store guarded)

    const u16* arow = Ah + (tile * 16 + m16) * AH_PITCH + quad * 8;
    short8 a[6];
#pragma unroll
    for (int kc = 0; kc < 3; kc++) a[kc] = *(const short8*)(arow + kc * 32);
#pragma unroll
    for (int kc = 0; kc < 3; kc++) {         // x-row frags span lo/hi arrays
        int off = kc * 32 + quad * 8;        // element offset 0..95 (mult of 8)
        const u16* p = (off < DH) ? (xh_lo + (size_t)nn * DH + off)
                                  : (xh_hi + (size_t)nn * DH + (off - DH));
        a[3 + kc] = *(const short8*)p;       // 16 B aligned
    }

#pragma unroll
    for (int jt = 0; jt < 4; jt++) {
        const int jtt = jt0 + jt;
        f32x4 acc = {0.0f, 0.0f, 0.0f, 0.0f};
#pragma unroll
        for (int kc = 0; kc < 6; kc++) {
            short8 bfrag = *(const short8*)(Wfrag + ((jtt * 6 + kc) * 64 + lane) * 8);
            acc = __builtin_amdgcn_mfma_f32_16x16x32_bf16(a[kc], bfrag, acc, 0, 0, 0);
        }
        const int jj = jtt * 16 + m16;       // col = lane&15
        const float bj = bl[jj];
#pragma unroll
        for (int r = 0; r < 4; r++) {
            int row = quad * 4 + r;
            int n = tilebase + row;
            if (n < N_NODES)
                out[(size_t)n * D_OUT + jj] = fmaxf(acc[r] + bj, 0.0f);
        }
    }
}

extern "C" void kernel_launch(void* const* d_in, const int* in_sizes, int n_in,
                              void* d_out, int out_size, void* d_ws, size_t ws_size,
                              hipStream_t stream) {
    const float* x   = (const float*)d_in[0];
    const int* eidx  = (const int*)d_in[1];
    const float* Wl  = (const float*)d_in[2];
    const float* bl  = (const float*)d_in[3];
    const float* Wr  = (const float*)d_in[4];
    float* out = (float*)d_out;

    const int* src = eidx;                // edge_index[0]
    const int* dst = eidx + N_EDGES;      // edge_index[1]

    // ws layout (byte offsets) — no zero-init needed anywhere:
    //   binbuf    0          25,624,576 B (782*256*32 u32, 128 B cells)
    //   cnts      25,624,576    400,384 B (782*256 u16, fully overwritten)
    //   xh_lo     26,025,088  4,800,000 B (bf16 cols 0..47)   [16-aligned]
    //   xh_hi     30,825,088  4,800,000 B (bf16 cols 48..95)  [16-aligned]
    //   Wfrag     35,625,088     49,152 B                     [16-aligned]
    char* ws = (char*)d_ws;
    unsigned* binbuf = (unsigned*)ws;
    u16*      cnts   = (u16*)(ws + 25624576);
    u16*      xh_lo  = (u16*)(ws + 26025088);
    u16*      xh_hi  = (u16*)(ws + 30825088);
    u16*      Wfrag  = (u16*)(ws + 35625088);

    {
        dim3 grid(PART_BLOCKS + CONV_BLOCKS + WCONV_BLOCKS);   // 2612
        sage_part_conv<<<grid, 256, 0, stream>>>(src, dst, x, Wl, Wr,
                                                 cnts, binbuf, xh_lo, xh_hi, Wfrag);
    }
    {
        dim3 grid(AG_BLOCKS);                                  // 782
        sage_agg_gemm<<<grid, 512, 0, stream>>>(xh_lo, xh_hi, cnts, binbuf,
                                                Wfrag, bl, out);
    }
}